// Round 4
// baseline (485.355 us; speedup 1.0000x reference)
//
#include <hip/hip_runtime.h>

// TGNN encoder, fused single kernel: one block per batch row.
// B=1024, N=200, DN=DT=128, M=384.
// d_out layout: [ out (1024*128 f32) | attn_w (1024*200 f32) ]
//
// R4: key data staged via __builtin_amdgcn_global_load_lds (DMA, zero VGPR)
//     into a double-buffered LDS tile (8 keys x 3 arrays = 12 KB/chunk).
//     R3's register-chunking pushed VGPR to 176 -> occupancy 11.6%; DMA
//     staging gives loads-in-flight without registers. Each wave computes
//     2 keys/chunk from LDS (ds_read_b64 + interleaved butterflies).
//     FC GEMV unrolls capped (#pragma unroll 4) to keep VGPR <= 128.

constexpr int B_  = 1024;
constexpr int N_  = 200;
constexpr int DN_ = 128;
constexpr int M_  = 384;     // DN + DN + DT
constexpr int BDIM = 256;    // 4 waves
constexpr int CK   = 8;      // keys per chunk
constexpr int NCH  = N_ / CK; // 25 chunks

__device__ __forceinline__ float wave_sum(float v) {
#pragma unroll
    for (int off = 32; off > 0; off >>= 1)
        v += __shfl_xor(v, off, 64);
    return v;
}

// async 16B/lane global->LDS copy: lane i of the wave reads g+4*i floats,
// HW writes LDS at (uniform) l + 16*i bytes. 1 KB per wave-issue.
__device__ __forceinline__ void async_cp16(const float* g, float* l) {
    __builtin_amdgcn_global_load_lds(
        (const __attribute__((address_space(1))) void*)g,
        (__attribute__((address_space(3))) void*)l, 16, 0, 0);
}

__global__ __launch_bounds__(BDIM) void tgnn_kernel(
    const float* __restrict__ src,      // (B, DN)
    const float* __restrict__ src_t,    // (B, 1, DT)
    const float* __restrict__ seq,      // (B, N, DN)
    const float* __restrict__ seq_t,    // (B, N, DT)
    const float* __restrict__ seq_e,    // (B, N, DN)
    const int*   __restrict__ mask,     // (B, N) int32 (bool)
    const float* __restrict__ shared_attn, // (2M,)
    const float* __restrict__ fc_w,     // (M, M)
    const float* __restrict__ ln_g,     // (M,)
    const float* __restrict__ ln_b,     // (M,)
    const float* __restrict__ w1,       // (2DN, M+DN) = (256, 512)
    const float* __restrict__ w2,       // (DN, 2DN)   = (128, 256)
    float* __restrict__ out,            // (B, DN)
    float* __restrict__ attn_out)       // (B, N)
{
    const int b    = blockIdx.x;
    const int tid  = threadIdx.x;
    const int wave = tid >> 6;
    const int lane = tid & 63;
    const int d0   = 2 * lane;      // this lane's element pair within a 128-slice

    // stage[buf] layout = exact copy of global: [seq 8x128 | seq_e 8x128 | seq_t 8x128]
    __shared__ __align__(16) float s_stage[2][3 * CK * DN_];   // 24 KB
    __shared__ int   s_mask[N_];
    __shared__ float s_p[N_];                     // unnormalized exp(score)
    __shared__ __align__(16) float s_q[M_];       // q = [src, 0, src_t]
    __shared__ float s_oa[4][M_];                 // per-wave attention accumulators
    __shared__ __align__(16) float s_outattn[M_]; // attn @ k
    __shared__ __align__(16) float s_y[M_ + DN_]; // LN output, then concat src
    __shared__ __align__(16) float s_h[2 * DN_];  // relu(x @ w1.T)
    __shared__ float s_red[8];

    // ---- stage q + mask into LDS ----
    if (tid < 128) {
        s_q[tid]       = src[b * DN_ + tid];
        s_q[128 + tid] = 0.0f;
        s_q[256 + tid] = src_t[b * DN_ + tid];
    }
    for (int n = tid; n < N_; n += BDIM)
        s_mask[n] = mask[b * N_ + n];

    // ---- per-lane wk fragment ----
    const float* wq = shared_attn;        // [0, M)
    const float* wk = shared_attn + M_;   // [M, 2M)
    const float wk0 = wk[d0],       wk1 = wk[d0 + 1];
    const float wk2 = wk[128 + d0], wk3 = wk[128 + d0 + 1];
    const float wk4 = wk[256 + d0], wk5 = wk[256 + d0 + 1];

    // ---- q-side score (constant over n) ----
    float qpart = src[b * DN_ + d0]     * wq[d0]
                + src[b * DN_ + d0 + 1] * wq[d0 + 1]
                + src_t[b * DN_ + d0]     * wq[256 + d0]
                + src_t[b * DN_ + d0 + 1] * wq[256 + d0 + 1];
    const float qdot = wave_sum(qpart);

    // ---- DMA staging: chunk c covers keys [c*8, c*8+8) ----
    // 12 x 1KB issues per chunk; wave w issues i = w*3 + r, r=0..2.
    // issue i: array arr=i/4 (0:seq 1:seq_e 2:seq_t), float offset (i%4)*256.
    auto stage_chunk = [&](int c, int buf) {
        const long rowbase = (long)(b * N_ + c * CK) * DN_;
#pragma unroll
        for (int r = 0; r < 3; ++r) {
            const int i   = wave * 3 + r;
            const int arr = i >> 2;
            const int off = (i & 3) * 256;
            const float* gsrc = (arr == 0 ? seq : arr == 1 ? seq_e : seq_t)
                                + rowbase + off + lane * 4;
            async_cp16(gsrc, &s_stage[buf][arr * (CK * DN_) + off]);
        }
    };

    stage_chunk(0, 0);
    stage_chunk(1, 1);

    // ---- fused score + weighted-sum over chunks ----
    float o0 = 0.f, o1 = 0.f, o2 = 0.f, o3 = 0.f, o4 = 0.f, o5 = 0.f;
    float lsum = 0.f;
    const int j0 = wave * 2;            // this wave's 2 keys within each chunk
    for (int c = 0; c < NCH; ++c) {
        __syncthreads();                // drains DMA for chunk c (and c+1)
        const float* buf = s_stage[c & 1];
        const float2 a0 = *(const float2*)&buf[0 * (CK*DN_) + (j0    ) * DN_ + d0];
        const float2 ea0= *(const float2*)&buf[1 * (CK*DN_) + (j0    ) * DN_ + d0];
        const float2 t0 = *(const float2*)&buf[2 * (CK*DN_) + (j0    ) * DN_ + d0];
        const float2 a1 = *(const float2*)&buf[0 * (CK*DN_) + (j0 + 1) * DN_ + d0];
        const float2 ea1= *(const float2*)&buf[1 * (CK*DN_) + (j0 + 1) * DN_ + d0];
        const float2 t1 = *(const float2*)&buf[2 * (CK*DN_) + (j0 + 1) * DN_ + d0];
        float sc0 = a0.x * wk0 + a0.y * wk1 + ea0.x * wk2 + ea0.y * wk3
                  + t0.x * wk4 + t0.y * wk5;
        float sc1 = a1.x * wk0 + a1.y * wk1 + ea1.x * wk2 + ea1.y * wk3
                  + t1.x * wk4 + t1.y * wk5;
#pragma unroll
        for (int off = 32; off > 0; off >>= 1) {
            sc0 += __shfl_xor(sc0, off, 64);
            sc1 += __shfl_xor(sc1, off, 64);
        }
        const int n0 = c * CK + j0;
        const float p0 = s_mask[n0]     ? 0.0f : __expf(sc0 + qdot);
        const float p1 = s_mask[n0 + 1] ? 0.0f : __expf(sc1 + qdot);
        if (lane == 0) { s_p[n0] = p0; s_p[n0 + 1] = p1; }
        lsum += p0 + p1;
        o0 += p0 * a0.x + p1 * a1.x;  o1 += p0 * a0.y + p1 * a1.y;
        o2 += p0 * ea0.x + p1 * ea1.x; o3 += p0 * ea0.y + p1 * ea1.y;
        o4 += p0 * t0.x + p1 * t1.x;  o5 += p0 * t0.y + p1 * t1.y;
        __syncthreads();                // all waves done reading buf[c&1]
        if (c + 2 < NCH) stage_chunk(c + 2, c & 1);
    }

    // ---- combine 4 waves ----
    if (lane == 0) s_red[wave] = lsum;
    s_oa[wave][d0]           = o0; s_oa[wave][d0 + 1]       = o1;
    s_oa[wave][128 + d0]     = o2; s_oa[wave][128 + d0 + 1] = o3;
    s_oa[wave][256 + d0]     = o4; s_oa[wave][256 + d0 + 1] = o5;
    __syncthreads();

    const float Z    = s_red[0] + s_red[1] + s_red[2] + s_red[3];
    const float invZ = 1.0f / Z;

    for (int j = tid; j < M_; j += BDIM)
        s_outattn[j] = (s_oa[0][j] + s_oa[1][j] + s_oa[2][j] + s_oa[3][j]) * invZ;
    for (int n = tid; n < N_; n += BDIM)
        attn_out[b * N_ + n] = s_p[n] * invZ;
    __syncthreads();

    // ---- fc: s_y[i] = dot(s_outattn, fc_w[i,:]) + q[i] ----
    const float4* xa = (const float4*)s_outattn;
    for (int i = tid; i < M_; i += BDIM) {
        const float4* row = (const float4*)&fc_w[i * M_];
        float acc = 0.f;
#pragma unroll 4
        for (int j = 0; j < M_ / 4; ++j) {
            const float4 w = row[j];
            const float4 x = xa[j];
            acc += w.x * x.x + w.y * x.y + w.z * x.z + w.w * x.w;
        }
        s_y[i] = acc + s_q[i];
    }
    __syncthreads();

    // ---- layer norm over M ----
    float ls = 0.f, lq = 0.f;
    for (int j = tid; j < M_; j += BDIM) {
        const float v = s_y[j];
        ls += v; lq += v * v;
    }
    ls = wave_sum(ls); lq = wave_sum(lq);
    if (lane == 0) { s_red[wave] = ls; s_red[4 + wave] = lq; }
    __syncthreads();
    const float mean = (s_red[0] + s_red[1] + s_red[2] + s_red[3]) * (1.0f / M_);
    const float msq  = (s_red[4] + s_red[5] + s_red[6] + s_red[7]) * (1.0f / M_);
    const float rstd = rsqrtf(msq - mean * mean + 1e-5f);
    for (int j = tid; j < M_; j += BDIM)
        s_y[j] = (s_y[j] - mean) * rstd * ln_g[j] + ln_b[j];
    if (tid < 128)
        s_y[M_ + tid] = s_q[tid];               // concat src
    __syncthreads();

    // ---- agg fc1: s_h[i] = relu(dot(s_y[512], w1[i,:])) ----
    {
        const float4* xb = (const float4*)s_y;
        const float4* row = (const float4*)&w1[tid * (M_ + DN_)];
        float acc = 0.f;
#pragma unroll 4
        for (int j = 0; j < (M_ + DN_) / 4; ++j) {
            const float4 w = row[j];
            const float4 x = xb[j];
            acc += w.x * x.x + w.y * x.y + w.z * x.z + w.w * x.w;
        }
        s_h[tid] = fmaxf(acc, 0.0f);
    }
    __syncthreads();

    // ---- agg fc2: out[i] = dot(s_h[256], w2[i,:]) ----
    if (tid < DN_) {
        const float4* xc = (const float4*)s_h;
        const float4* row = (const float4*)&w2[tid * (2 * DN_)];
        float acc = 0.f;
#pragma unroll 4
        for (int j = 0; j < (2 * DN_) / 4; ++j) {
            const float4 w = row[j];
            const float4 x = xc[j];
            acc += w.x * x.x + w.y * x.y + w.z * x.z + w.w * x.w;
        }
        out[b * DN_ + tid] = acc;
    }
}

extern "C" void kernel_launch(void* const* d_in, const int* in_sizes, int n_in,
                              void* d_out, int out_size, void* d_ws, size_t ws_size,
                              hipStream_t stream) {
    const float* src         = (const float*)d_in[0];
    const float* src_t       = (const float*)d_in[1];
    const float* seq         = (const float*)d_in[2];
    const float* seq_t       = (const float*)d_in[3];
    const float* seq_e       = (const float*)d_in[4];
    const int*   mask        = (const int*)  d_in[5];
    const float* shared_attn = (const float*)d_in[6];
    const float* fc_w        = (const float*)d_in[7];
    const float* ln_g        = (const float*)d_in[8];
    const float* ln_b        = (const float*)d_in[9];
    const float* w1          = (const float*)d_in[10];
    const float* w2          = (const float*)d_in[11];

    float* outp     = (float*)d_out;             // (B, DN)
    float* attn_out = (float*)d_out + B_ * DN_;  // (B, N)

    tgnn_kernel<<<B_, BDIM, 0, stream>>>(src, src_t, seq, seq_t, seq_e, mask,
                                         shared_attn, fc_w, ln_g, ln_b, w1, w2,
                                         outp, attn_out);
}

// Round 5
// 430.154 us; speedup vs baseline: 1.1283x; 1.1283x over previous
//
#include <hip/hip_runtime.h>

// TGNN encoder, fused single kernel: one block per batch row.
// B=1024, N=200, DN=DT=128, M=384.
// d_out layout: [ out (1024*128 f32) | attn_w (1024*200 f32) ]
//
// R5: streaming path rebuilt with zero cross-lane/barrier deps:
//   - masked keys (~50%) never loaded (attn weight is exactly 0):
//     ordered ballot-compaction -> active list, traffic 315->~158 MB.
//   - phase 1: thread-per-active-key row dot (16 float4 loads in flight,
//     wk broadcast from LDS, no shuffles, no barriers).
//   - phase 2: lane-owns-dims re-read (L3-hot), p broadcast from LDS,
//     8-key unroll -> 24 independent loads in flight, no shuffles.
//   R1/R3/R4 all capped at ~700 GB/s because shuffle chains or barrier
//   drains sat between every small load batch.

constexpr int B_  = 1024;
constexpr int N_  = 200;
constexpr int DN_ = 128;
constexpr int M_  = 384;     // DN + DN + DT
constexpr int BDIM = 256;    // 4 waves

__device__ __forceinline__ float wave_sum(float v) {
#pragma unroll
    for (int off = 32; off > 0; off >>= 1)
        v += __shfl_xor(v, off, 64);
    return v;
}

__global__ __launch_bounds__(BDIM) void tgnn_kernel(
    const float* __restrict__ src,      // (B, DN)
    const float* __restrict__ src_t,    // (B, 1, DT)
    const float* __restrict__ seq,      // (B, N, DN)
    const float* __restrict__ seq_t,    // (B, N, DT)
    const float* __restrict__ seq_e,    // (B, N, DN)
    const int*   __restrict__ mask,     // (B, N) int32 (bool)
    const float* __restrict__ shared_attn, // (2M,)
    const float* __restrict__ fc_w,     // (M, M)
    const float* __restrict__ ln_g,     // (M,)
    const float* __restrict__ ln_b,     // (M,)
    const float* __restrict__ w1,       // (2DN, M+DN) = (256, 512)
    const float* __restrict__ w2,       // (DN, 2DN)   = (128, 256)
    float* __restrict__ out,            // (B, DN)
    float* __restrict__ attn_out)       // (B, N)
{
    const int b    = blockIdx.x;
    const int tid  = threadIdx.x;
    const int wave = tid >> 6;
    const int lane = tid & 63;
    const int d0   = 2 * lane;

    __shared__ __align__(16) float s_wk[M_];      // wk staged (broadcast source)
    __shared__ float s_p[N_];                     // p by key (0 for masked)
    __shared__ float s_pa[N_];                    // p by active slot
    __shared__ int   s_idx[N_];                   // active slot -> key
    __shared__ int   s_wcnt[4];                   // per-wave active counts
    __shared__ __align__(16) float s_q[M_];       // q = [src, 0, src_t]
    __shared__ float s_oa[4][M_];                 // per-wave attention accumulators
    __shared__ __align__(16) float s_outattn[M_];
    __shared__ __align__(16) float s_y[M_ + DN_];
    __shared__ __align__(16) float s_h[2 * DN_];
    __shared__ float s_red[8];

    // ---- stage wk, q; init p ----
    for (int j = tid; j < M_; j += BDIM) s_wk[j] = shared_attn[M_ + j];
    for (int n = tid; n < N_; n += BDIM) s_p[n] = 0.0f;
    if (tid < 128) {
        s_q[tid]       = src[b * DN_ + tid];
        s_q[128 + tid] = 0.0f;
        s_q[256 + tid] = src_t[b * DN_ + tid];
    }

    // ---- q-side score (constant over n), redundant per wave ----
    const float* wq = shared_attn;
    float qpart = src[b * DN_ + d0]       * wq[d0]
                + src[b * DN_ + d0 + 1]   * wq[d0 + 1]
                + src_t[b * DN_ + d0]     * wq[256 + d0]
                + src_t[b * DN_ + d0 + 1] * wq[256 + d0 + 1];
    const float qdot = wave_sum(qpart);

    // ---- ordered compaction of active (unmasked) keys ----
    const bool active = (tid < N_) && (mask[b * N_ + tid] == 0);
    const unsigned long long bal = __ballot(active);
    if (lane == 0) s_wcnt[wave] = __popcll(bal);
    __syncthreads();
    int base = 0;
#pragma unroll
    for (int w = 0; w < 4; ++w) if (w < wave) base += s_wcnt[w];
    const int A = s_wcnt[0] + s_wcnt[1] + s_wcnt[2] + s_wcnt[3];
    if (active) {
        const int pos = base + __popcll(bal & ((1ull << lane) - 1ull));
        s_idx[pos] = tid;
    }
    __syncthreads();

    // ---- phase 1: thread t < A computes full score of key s_idx[t] ----
    float p_t = 0.0f;
    if (tid < A) {
        const int key = s_idx[tid];
        const size_t rb = (size_t)(b * N_ + key) * DN_;
        const float4* ra = (const float4*)(seq   + rb);
        const float4* re = (const float4*)(seq_e + rb);
        const float4* rt = (const float4*)(seq_t + rb);
        const float4* wk4 = (const float4*)s_wk;   // 96 float4: [seq|seq_e|seq_t]
        float acc0 = 0.f, acc1 = 0.f, acc2 = 0.f;
#pragma unroll 1
        for (int g = 0; g < 2; ++g) {
            float4 x[16];
#pragma unroll
            for (int u = 0; u < 16; ++u) x[u] = ra[g * 16 + u];
#pragma unroll
            for (int u = 0; u < 16; ++u) {
                const float4 w = wk4[g * 16 + u];
                acc0 += x[u].x * w.x + x[u].y * w.y + x[u].z * w.z + x[u].w * w.w;
            }
        }
#pragma unroll 1
        for (int g = 0; g < 2; ++g) {
            float4 x[16];
#pragma unroll
            for (int u = 0; u < 16; ++u) x[u] = re[g * 16 + u];
#pragma unroll
            for (int u = 0; u < 16; ++u) {
                const float4 w = wk4[32 + g * 16 + u];
                acc1 += x[u].x * w.x + x[u].y * w.y + x[u].z * w.z + x[u].w * w.w;
            }
        }
#pragma unroll 1
        for (int g = 0; g < 2; ++g) {
            float4 x[16];
#pragma unroll
            for (int u = 0; u < 16; ++u) x[u] = rt[g * 16 + u];
#pragma unroll
            for (int u = 0; u < 16; ++u) {
                const float4 w = wk4[64 + g * 16 + u];
                acc2 += x[u].x * w.x + x[u].y * w.y + x[u].z * w.z + x[u].w * w.w;
            }
        }
        p_t = __expf(acc0 + acc1 + acc2 + qdot);
        s_p[key]  = p_t;
        s_pa[tid] = p_t;
    }

    // ---- Z reduction ----
    const float zs = wave_sum(p_t);
    if (lane == 0) s_red[wave] = zs;
    __syncthreads();
    const float Z    = s_red[0] + s_red[1] + s_red[2] + s_red[3];
    const float invZ = 1.0f / Z;

    // ---- phase 2: weighted sum over active keys (L3-hot re-read) ----
    float o0 = 0.f, o1 = 0.f, o2 = 0.f, o3 = 0.f, o4 = 0.f, o5 = 0.f;
    const int lo = (A * wave) >> 2, hi = (A * (wave + 1)) >> 2;
    int s = lo;
    for (; s + 8 <= hi; s += 8) {
#pragma unroll
        for (int u = 0; u < 8; ++u) {
            const int   key = s_idx[s + u];
            const float p   = s_pa[s + u];
            const size_t rb = (size_t)(b * N_ + key) * DN_ + d0;
            const float2 a  = *(const float2*)&seq  [rb];
            const float2 e  = *(const float2*)&seq_e[rb];
            const float2 t  = *(const float2*)&seq_t[rb];
            o0 += p * a.x; o1 += p * a.y;
            o2 += p * e.x; o3 += p * e.y;
            o4 += p * t.x; o5 += p * t.y;
        }
    }
    for (; s < hi; ++s) {
        const int   key = s_idx[s];
        const float p   = s_pa[s];
        const size_t rb = (size_t)(b * N_ + key) * DN_ + d0;
        const float2 a  = *(const float2*)&seq  [rb];
        const float2 e  = *(const float2*)&seq_e[rb];
        const float2 t  = *(const float2*)&seq_t[rb];
        o0 += p * a.x; o1 += p * a.y;
        o2 += p * e.x; o3 += p * e.y;
        o4 += p * t.x; o5 += p * t.y;
    }

    s_oa[wave][d0]           = o0; s_oa[wave][d0 + 1]       = o1;
    s_oa[wave][128 + d0]     = o2; s_oa[wave][128 + d0 + 1] = o3;
    s_oa[wave][256 + d0]     = o4; s_oa[wave][256 + d0 + 1] = o5;
    __syncthreads();

    for (int j = tid; j < M_; j += BDIM)
        s_outattn[j] = (s_oa[0][j] + s_oa[1][j] + s_oa[2][j] + s_oa[3][j]) * invZ;
    for (int n = tid; n < N_; n += BDIM)
        attn_out[b * N_ + n] = s_p[n] * invZ;
    __syncthreads();

    // ---- fc: s_y[i] = dot(s_outattn, fc_w[i,:]) + q[i] ----
    const float4* xa = (const float4*)s_outattn;
    for (int i = tid; i < M_; i += BDIM) {
        const float4* row = (const float4*)&fc_w[i * M_];
        float acc = 0.f;
#pragma unroll 8
        for (int j = 0; j < M_ / 4; ++j) {
            const float4 w = row[j];
            const float4 x = xa[j];
            acc += w.x * x.x + w.y * x.y + w.z * x.z + w.w * x.w;
        }
        s_y[i] = acc + s_q[i];
    }
    __syncthreads();

    // ---- layer norm over M ----
    float ls = 0.f, lq = 0.f;
    for (int j = tid; j < M_; j += BDIM) {
        const float v = s_y[j];
        ls += v; lq += v * v;
    }
    ls = wave_sum(ls); lq = wave_sum(lq);
    if (lane == 0) { s_red[wave] = ls; s_red[4 + wave] = lq; }
    __syncthreads();
    const float mean = (s_red[0] + s_red[1] + s_red[2] + s_red[3]) * (1.0f / M_);
    const float msq  = (s_red[4] + s_red[5] + s_red[6] + s_red[7]) * (1.0f / M_);
    const float rstd = rsqrtf(msq - mean * mean + 1e-5f);
    for (int j = tid; j < M_; j += BDIM)
        s_y[j] = (s_y[j] - mean) * rstd * ln_g[j] + ln_b[j];
    if (tid < 128)
        s_y[M_ + tid] = s_q[tid];               // concat src
    __syncthreads();

    // ---- agg fc1: s_h[i] = relu(dot(s_y[512], w1[i,:])) ----
    {
        const float4* xb = (const float4*)s_y;
        const float4* row = (const float4*)&w1[tid * (M_ + DN_)];
        float acc = 0.f;
#pragma unroll 8
        for (int j = 0; j < (M_ + DN_) / 4; ++j) {
            const float4 w = row[j];
            const float4 x = xb[j];
            acc += w.x * x.x + w.y * x.y + w.z * x.z + w.w * x.w;
        }
        s_h[tid] = fmaxf(acc, 0.0f);
    }
    __syncthreads();

    // ---- agg fc2: out[i] = dot(s_h[256], w2[i,:]) ----
    if (tid < DN_) {
        const float4* xc = (const float4*)s_h;
        const float4* row = (const float4*)&w2[tid * (2 * DN_)];
        float acc = 0.f;
#pragma unroll 8
        for (int j = 0; j < (2 * DN_) / 4; ++j) {
            const float4 w = row[j];
            const float4 x = xc[j];
            acc += w.x * x.x + w.y * x.y + w.z * x.z + w.w * x.w;
        }
        out[b * DN_ + tid] = acc;
    }
}

extern "C" void kernel_launch(void* const* d_in, const int* in_sizes, int n_in,
                              void* d_out, int out_size, void* d_ws, size_t ws_size,
                              hipStream_t stream) {
    const float* src         = (const float*)d_in[0];
    const float* src_t       = (const float*)d_in[1];
    const float* seq         = (const float*)d_in[2];
    const float* seq_t       = (const float*)d_in[3];
    const float* seq_e       = (const float*)d_in[4];
    const int*   mask        = (const int*)  d_in[5];
    const float* shared_attn = (const float*)d_in[6];
    const float* fc_w        = (const float*)d_in[7];
    const float* ln_g        = (const float*)d_in[8];
    const float* ln_b        = (const float*)d_in[9];
    const float* w1          = (const float*)d_in[10];
    const float* w2          = (const float*)d_in[11];

    float* outp     = (float*)d_out;             // (B, DN)
    float* attn_out = (float*)d_out + B_ * DN_;  // (B, N)

    tgnn_kernel<<<B_, BDIM, 0, stream>>>(src, src_t, seq, seq_t, seq_e, mask,
                                         shared_attn, fc_w, ln_g, ln_b, w1, w2,
                                         outp, attn_out);
}